// Round 1
// baseline (77.984 us; speedup 1.0000x reference)
//
#include <hip/hip_runtime.h>

typedef _Float16 f16;
typedef __attribute__((ext_vector_type(8))) _Float16 f16x8;
typedef __attribute__((ext_vector_type(4))) _Float16 f16x4;
typedef __attribute__((ext_vector_type(4))) float f32x4;

#define NB 16
#define LSEQ 2048
#define DIM 64
#define KVB 64
#define QT 64
#define PITCH 72  // f16 elems per LDS row (144 B): keeps ds_read_b128 16B-aligned, spreads banks

__global__ __launch_bounds__(256, 2) void attn_fwd(
    const float* __restrict__ qg, const float* __restrict__ kg,
    const float* __restrict__ vg, const int* __restrict__ vlg,
    float* __restrict__ outg)
{
    __shared__ alignas(16) f16 kld[KVB * PITCH];      // K[key][d]
    __shared__ alignas(16) f16 vtld[DIM * PITCH];     // V^T[dv][key]
    __shared__ alignas(16) f16 pld[4 * 16 * PITCH];   // per-wave P[q][key]

    const int tid  = threadIdx.x;
    const int wid  = tid >> 6;
    const int lane = tid & 63;
    const int r    = lane & 15;
    const int hi   = lane >> 4;

    const int b  = blockIdx.x >> 5;   // 32 q-tiles per batch
    const int qt = blockIdx.x & 31;
    const int qw = qt * QT + wid * 16;  // wave's first query row

    // ---- Q fragments in registers (f32 -> f16) ----
    // B-operand layout for mfma(K, Q): lane holds q-col = r, d = ks*32 + hi*8 + j
    f16x8 qf[2];
    const float* qrow = qg + ((size_t)(b * LSEQ + qw + r)) * DIM;
#pragma unroll
    for (int ks = 0; ks < 2; ++ks) {
        const float* p = qrow + ks * 32 + hi * 8;
        float4 x = *(const float4*)p;
        float4 y = *(const float4*)(p + 4);
        f16x8 t;
        t[0]=(f16)x.x; t[1]=(f16)x.y; t[2]=(f16)x.z; t[3]=(f16)x.w;
        t[4]=(f16)y.x; t[5]=(f16)y.y; t[6]=(f16)y.z; t[7]=(f16)y.w;
        qf[ks] = t;
    }
    const int vl = vlg[b * LSEQ + qw + r];  // this lane's query valid_len

    float m_run = -INFINITY;
    float l_run = 0.0f;
    f32x4 o[4];
#pragma unroll
    for (int dt = 0; dt < 4; ++dt) o[dt] = f32x4{0.f, 0.f, 0.f, 0.f};

    f16* pw = pld + wid * (16 * PITCH);
    const float* kbase = kg + ((size_t)b * LSEQ) * DIM;
    const float* vbase = vg + ((size_t)b * LSEQ) * DIM;

    for (int kv0 = 0; kv0 < LSEQ; kv0 += KVB) {
        __syncthreads();  // all waves done reading previous K/V^T tile

        // ---- stage K tile: 1024 float4 chunks over 256 threads ----
#pragma unroll
        for (int it = 0; it < 4; ++it) {
            int cc = tid + it * 256;
            int kr = cc >> 4;
            int d0 = (cc & 15) * 4;
            float4 x = *(const float4*)(kbase + (size_t)(kv0 + kr) * DIM + d0);
            f16x4 t;
            t[0]=(f16)x.x; t[1]=(f16)x.y; t[2]=(f16)x.z; t[3]=(f16)x.w;
            *(f16x4*)(kld + kr * PITCH + d0) = t;
        }
        // ---- stage V^T tile via in-register 4x4 transpose ----
        {
            int db  = tid & 15;   // dv block (4 dv)
            int kb4 = tid >> 4;   // key block (4 keys)
            float rr[4][4];
#pragma unroll
            for (int i = 0; i < 4; ++i) {
                float4 x = *(const float4*)(vbase + (size_t)(kv0 + kb4 * 4 + i) * DIM + db * 4);
                rr[i][0]=x.x; rr[i][1]=x.y; rr[i][2]=x.z; rr[i][3]=x.w;
            }
#pragma unroll
            for (int j = 0; j < 4; ++j) {
                f16x4 t;
                t[0]=(f16)rr[0][j]; t[1]=(f16)rr[1][j]; t[2]=(f16)rr[2][j]; t[3]=(f16)rr[3][j];
                *(f16x4*)(vtld + (db * 4 + j) * PITCH + kb4 * 4) = t;
            }
        }
        __syncthreads();  // tile staged

        // ---- S^T = mfma(K, Q): lane holds query col r, key rows kt*16 + 4*hi + g ----
        f32x4 st[4];
#pragma unroll
        for (int kt = 0; kt < 4; ++kt) {
            f32x4 acc = f32x4{0.f, 0.f, 0.f, 0.f};
#pragma unroll
            for (int ks = 0; ks < 2; ++ks) {
                f16x8 kf = *(const f16x8*)(kld + (kt * 16 + r) * PITCH + ks * 32 + hi * 8);
                acc = __builtin_amdgcn_mfma_f32_16x16x32_f16(kf, qf[ks], acc, 0, 0, 0);
            }
            st[kt] = acc;
        }

        // ---- mask + online softmax (query = qw + r; keys split across 4-lane group) ----
        float tmax = -INFINITY;
#pragma unroll
        for (int kt = 0; kt < 4; ++kt)
#pragma unroll
            for (int g = 0; g < 4; ++g) {
                int key = kv0 + kt * 16 + hi * 4 + g;
                float s = (key < vl) ? st[kt][g] : -1e9f;  // reference NEG semantics
                st[kt][g] = s;
                tmax = fmaxf(tmax, s);
            }
        tmax = fmaxf(tmax, __shfl_xor(tmax, 16));
        tmax = fmaxf(tmax, __shfl_xor(tmax, 32));
        float m_new = fmaxf(m_run, tmax);
        float scale = __expf(m_run - m_new);  // first tile: exp(-inf)=0
        float tsum = 0.0f;
#pragma unroll
        for (int kt = 0; kt < 4; ++kt) {
            f16x4 pv;
#pragma unroll
            for (int g = 0; g < 4; ++g) {
                float p = __expf(st[kt][g] - m_new);  // all-masked row -> p=1 (uniform), matches ref
                tsum += p;
                pv[g] = (f16)p;
            }
            *(f16x4*)(pw + r * PITCH + kt * 16 + hi * 4) = pv;  // P[q=r][key]
        }
        tsum += __shfl_xor(tsum, 16);
        tsum += __shfl_xor(tsum, 32);
        l_run = l_run * scale + tsum;
        m_run = m_new;

        // ---- rescale O (O rows are queries 4*hi+g; softmax state lives in lane g' = 4*hi+g) ----
#pragma unroll
        for (int g = 0; g < 4; ++g) {
            float sc = __shfl(scale, hi * 4 + g);
#pragma unroll
            for (int dt = 0; dt < 4; ++dt) o[dt][g] *= sc;
        }

        // ---- PV: O += mfma(P, V) ; wave-private P round-trip (lgkmcnt only, no barrier) ----
#pragma unroll
        for (int ks = 0; ks < 2; ++ks) {
            f16x8 pa = *(const f16x8*)(pw + r * PITCH + ks * 32 + hi * 8);
#pragma unroll
            for (int dt = 0; dt < 4; ++dt) {
                f16x8 vf = *(const f16x8*)(vtld + (dt * 16 + r) * PITCH + ks * 32 + hi * 8);
                o[dt] = __builtin_amdgcn_mfma_f32_16x16x32_f16(pa, vf, o[dt], 0, 0, 0);
            }
        }
    }

    // ---- epilogue: divide by softmax denom, store f32 ----
    float inv = 1.0f / l_run;
    float* ob = outg + ((size_t)(b * LSEQ + qw)) * DIM;
#pragma unroll
    for (int g = 0; g < 4; ++g) {
        float iv = __shfl(inv, hi * 4 + g);
#pragma unroll
        for (int dt = 0; dt < 4; ++dt)
            ob[(hi * 4 + g) * DIM + dt * 16 + r] = o[dt][g] * iv;
    }
}

extern "C" void kernel_launch(void* const* d_in, const int* in_sizes, int n_in,
                              void* d_out, int out_size, void* d_ws, size_t ws_size,
                              hipStream_t stream) {
    const float* q  = (const float*)d_in[0];
    const float* k  = (const float*)d_in[1];
    const float* v  = (const float*)d_in[2];
    const int*   vl = (const int*)d_in[3];
    float* out = (float*)d_out;

    dim3 grid(NB * (LSEQ / QT));  // 16 batches x 32 q-tiles = 512 blocks
    dim3 block(256);
    attn_fwd<<<grid, block, 0, stream>>>(q, k, v, vl, out);
}

// Round 2
// 61.606 us; speedup vs baseline: 1.2658x; 1.2658x over previous
//
#include <hip/hip_runtime.h>

typedef _Float16 f16;
typedef __attribute__((ext_vector_type(8))) _Float16 f16x8;
typedef __attribute__((ext_vector_type(4))) _Float16 f16x4;
typedef __attribute__((ext_vector_type(4))) float f32x4;

#define NB 16
#define LSEQ 2048
#define DIM 64
#define KVB 64
#define QT 64
#define NT (LSEQ / KVB)
#define PITCH 72  // f16/row (144B): 16B-aligned, rotates bank groups by 4/row
#define LOG2E 1.44269504088896340736f

__global__ __launch_bounds__(256, 2) void attn_fwd(
    const float* __restrict__ qg, const float* __restrict__ kg,
    const float* __restrict__ vg, const int* __restrict__ vlg,
    float* __restrict__ outg)
{
    __shared__ alignas(16) f16 kld[2][KVB * PITCH];   // K[key][d], double-buffered
    __shared__ alignas(16) f16 vtld[2][DIM * PITCH];  // V^T[dv][key], double-buffered
    __shared__ alignas(16) f16 pld[4 * 16 * PITCH];   // per-wave P[q][key]

    const int tid  = threadIdx.x;
    const int wid  = tid >> 6;
    const int lane = tid & 63;
    const int r    = lane & 15;
    const int hi   = lane >> 4;

    // XCD-aware swizzle: 512 blocks, 8 XCDs -> 2 batches per XCD (K+V=2MB fits 4MB L2)
    const int bid = blockIdx.x;
    const int xcd = bid & 7;
    const int idx = bid >> 3;            // 0..63 within XCD
    const int b   = xcd * 2 + (idx >> 5);
    const int qt  = idx & 31;
    const int qw  = qt * QT + wid * 16;  // wave's first query row (within batch)

    // staging assignments
    const int kb  = tid & 15;   // V: key block (4 keys)
    const int dvb = tid >> 4;   // V: dv block (4 dv)

    // ---- Q fragments (f32 -> f16): B-operand for mfma(K, Q); lane holds q-col r ----
    f16x8 qf[2];
    const float* qrow = qg + ((size_t)(b * LSEQ + qw + r)) * DIM;
#pragma unroll
    for (int ks = 0; ks < 2; ++ks) {
        f32x4 x = *(const f32x4*)(qrow + ks * 32 + hi * 8);
        f32x4 y = *(const f32x4*)(qrow + ks * 32 + hi * 8 + 4);
        f16x8 t;
        t[0]=(f16)x[0]; t[1]=(f16)x[1]; t[2]=(f16)x[2]; t[3]=(f16)x[3];
        t[4]=(f16)y[0]; t[5]=(f16)y[1]; t[6]=(f16)y[2]; t[7]=(f16)y[3];
        qf[ks] = t;
    }
    const int vl = vlg[b * LSEQ + qw + r];

    float m_run = -INFINITY;   // log2-domain running max
    float l_run = 0.0f;
    f32x4 o[4];
#pragma unroll
    for (int dt = 0; dt < 4; ++dt) o[dt] = f32x4{0.f, 0.f, 0.f, 0.f};

    f16* pw = pld + wid * (16 * PITCH);
    const float* kbase = kg + ((size_t)b * LSEQ) * DIM;
    const float* vbase = vg + ((size_t)b * LSEQ) * DIM;

    f32x4 kst[4], vst[4];

    // ---- prologue: load tile 0 -> regs, convert+write -> buf 0 ----
#pragma unroll
    for (int it = 0; it < 4; ++it) {
        int cc = tid + it * 256;
        kst[it] = *(const f32x4*)(kbase + (size_t)(cc >> 4) * DIM + (cc & 15) * 4);
    }
#pragma unroll
    for (int i = 0; i < 4; ++i)
        vst[i] = *(const f32x4*)(vbase + (size_t)(kb * 4 + i) * DIM + dvb * 4);
#pragma unroll
    for (int it = 0; it < 4; ++it) {
        int cc = tid + it * 256;
        f16x4 t;
        t[0]=(f16)kst[it][0]; t[1]=(f16)kst[it][1]; t[2]=(f16)kst[it][2]; t[3]=(f16)kst[it][3];
        *(f16x4*)(&kld[0][(cc >> 4) * PITCH + (cc & 15) * 4]) = t;
    }
#pragma unroll
    for (int j = 0; j < 4; ++j) {
        f16x4 t;
        t[0]=(f16)vst[0][j]; t[1]=(f16)vst[1][j]; t[2]=(f16)vst[2][j]; t[3]=(f16)vst[3][j];
        *(f16x4*)(&vtld[0][(dvb * 4 + j) * PITCH + kb * 4]) = t;
    }

    int c = 0;
    for (int t = 0; t < NT; ++t) {
        __syncthreads();  // buf[c] staged & prior reads of buf[c^1] done

        // ---- issue next tile's global loads (latency hides under compute) ----
        if (t + 1 < NT) {
            int kv0 = (t + 1) * KVB;
#pragma unroll
            for (int it = 0; it < 4; ++it) {
                int cc = tid + it * 256;
                kst[it] = *(const f32x4*)(kbase + (size_t)(kv0 + (cc >> 4)) * DIM + (cc & 15) * 4);
            }
#pragma unroll
            for (int i = 0; i < 4; ++i)
                vst[i] = *(const f32x4*)(vbase + (size_t)(kv0 + kb * 4 + i) * DIM + dvb * 4);
        }

        // ---- S^T = mfma(K, Q): lane holds query col r, key rows kt*16 + 4*hi + g ----
        f32x4 st[4];
        __builtin_amdgcn_s_setprio(1);
#pragma unroll
        for (int kt = 0; kt < 4; ++kt) {
            f32x4 acc = f32x4{0.f, 0.f, 0.f, 0.f};
#pragma unroll
            for (int ks = 0; ks < 2; ++ks) {
                f16x8 kf = *(const f16x8*)(&kld[c][(kt * 16 + r) * PITCH + ks * 32 + hi * 8]);
                acc = __builtin_amdgcn_mfma_f32_16x16x32_f16(kf, qf[ks], acc, 0, 0, 0);
            }
            st[kt] = acc;
        }
        __builtin_amdgcn_s_setprio(0);

        // ---- mask + online softmax in log2 domain ----
        const int kv0 = t * KVB;
        float tmax = -INFINITY;
#pragma unroll
        for (int kt = 0; kt < 4; ++kt)
#pragma unroll
            for (int g = 0; g < 4; ++g) {
                int key = kv0 + kt * 16 + hi * 4 + g;
                float s = (key < vl) ? st[kt][g] * LOG2E : -1.5e9f;
                st[kt][g] = s;
                tmax = fmaxf(tmax, s);
            }
        tmax = fmaxf(tmax, __shfl_xor(tmax, 16));
        tmax = fmaxf(tmax, __shfl_xor(tmax, 32));
        float m_new = fmaxf(m_run, tmax);
        float scale = exp2f(m_run - m_new);  // first tile: exp2(-inf)=0
        float tsum = 0.0f;
#pragma unroll
        for (int kt = 0; kt < 4; ++kt) {
            f16x4 pv;
#pragma unroll
            for (int g = 0; g < 4; ++g) {
                float p = exp2f(st[kt][g] - m_new);  // all-masked row -> p=1 (uniform), matches ref
                tsum += p;
                pv[g] = (f16)p;
            }
            *(f16x4*)(pw + r * PITCH + kt * 16 + hi * 4) = pv;  // P[q=r][key]
        }
        tsum += __shfl_xor(tsum, 16);
        tsum += __shfl_xor(tsum, 32);
        l_run = l_run * scale + tsum;
        m_run = m_new;

        // ---- rescale O (O cols g are queries 4*hi+g; state lives in lane 4*hi+g) ----
#pragma unroll
        for (int g = 0; g < 4; ++g) {
            float sc = __shfl(scale, hi * 4 + g);
#pragma unroll
            for (int dt = 0; dt < 4; ++dt) o[dt][g] *= sc;
        }

        // ---- PV: O += mfma(P, V); wave-private P round-trip (lgkmcnt only) ----
        __builtin_amdgcn_s_setprio(1);
#pragma unroll
        for (int ks = 0; ks < 2; ++ks) {
            f16x8 pa = *(const f16x8*)(pw + r * PITCH + ks * 32 + hi * 8);
#pragma unroll
            for (int dt = 0; dt < 4; ++dt) {
                f16x8 vf = *(const f16x8*)(&vtld[c][(dt * 16 + r) * PITCH + ks * 32 + hi * 8]);
                o[dt] = __builtin_amdgcn_mfma_f32_16x16x32_f16(pa, vf, o[dt], 0, 0, 0);
            }
        }
        __builtin_amdgcn_s_setprio(0);

        // ---- convert + write next tile into buf[c^1] ----
        if (t + 1 < NT) {
#pragma unroll
            for (int it = 0; it < 4; ++it) {
                int cc = tid + it * 256;
                f16x4 tt;
                tt[0]=(f16)kst[it][0]; tt[1]=(f16)kst[it][1]; tt[2]=(f16)kst[it][2]; tt[3]=(f16)kst[it][3];
                *(f16x4*)(&kld[c ^ 1][(cc >> 4) * PITCH + (cc & 15) * 4]) = tt;
            }
#pragma unroll
            for (int j = 0; j < 4; ++j) {
                f16x4 tt;
                tt[0]=(f16)vst[0][j]; tt[1]=(f16)vst[1][j]; tt[2]=(f16)vst[2][j]; tt[3]=(f16)vst[3][j];
                *(f16x4*)(&vtld[c ^ 1][(dvb * 4 + j) * PITCH + kb * 4]) = tt;
            }
        }
        c ^= 1;
    }

    // ---- epilogue ----
    float inv = 1.0f / l_run;
    float* ob = outg + ((size_t)(b * LSEQ + qw)) * DIM;
#pragma unroll
    for (int g = 0; g < 4; ++g) {
        float iv = __shfl(inv, hi * 4 + g);
#pragma unroll
        for (int dt = 0; dt < 4; ++dt)
            ob[(hi * 4 + g) * DIM + dt * 16 + r] = o[dt][g] * iv;
    }
}

extern "C" void kernel_launch(void* const* d_in, const int* in_sizes, int n_in,
                              void* d_out, int out_size, void* d_ws, size_t ws_size,
                              hipStream_t stream) {
    const float* q  = (const float*)d_in[0];
    const float* k  = (const float*)d_in[1];
    const float* v  = (const float*)d_in[2];
    const int*   vl = (const int*)d_in[3];
    float* out = (float*)d_out;

    dim3 grid(NB * (LSEQ / QT));  // 512 blocks
    dim3 block(256);
    attn_fwd<<<grid, block, 0, stream>>>(q, k, v, vl, out);
}